// Round 2
// baseline (11830.721 us; speedup 1.0000x reference)
//
#include <hip/hip_runtime.h>

static constexpr int Bsz = 512;
static constexpr int Tsz = 256;
static constexpr int Nsz = 128;
static constexpr int Msz = 256;

__device__ __forceinline__ float rcp_fast(float v){ return __builtin_amdgcn_rcpf(v); }
__device__ __forceinline__ float sigmoid_fast(float v){ return rcp_fast(1.0f + __expf(-v)); }
__device__ __forceinline__ float tanh_fast(float v){ return 1.0f - 2.0f * rcp_fast(1.0f + __expf(2.0f * v)); }
__device__ __forceinline__ unsigned short bf16r(float f){
  unsigned u = __float_as_uint(f);
  u += 0x7FFFu + ((u >> 16) & 1u);
  return (unsigned short)(u >> 16);
}

// ---------------------------------------------------------------------------
// K0: init fp32 ping-pong slot0 from inputs + bf16 HS slab t=0.
// HS layout: [t][b][j], j<256 -> h, j>=256 -> s  (bf16, stride 512)
// ---------------------------------------------------------------------------
__global__ __launch_bounds__(256) void k_init(const float* __restrict__ h_in,
                                              const float* __restrict__ s_in,
                                              float* __restrict__ hp,
                                              float* __restrict__ sp,
                                              unsigned short* __restrict__ HS){
  const int i = blockIdx.x * 256 + threadIdx.x;   // 0 .. B*M-1
  const float h = h_in[i];
  const float s = s_in[i];
  hp[i] = h;
  sp[i] = s;
  const int b = i >> 8;
  const int m = i & 255;
  unsigned short* row = HS + (size_t)b * 512;
  row[m]       = bf16r(h);
  row[256 + m] = bf16r(s);
}

// ---------------------------------------------------------------------------
// K1: Q[b][n][u] = exp( 2 * sum_t x[b][t][n] * Ue[t][u] )   (r2, pre-exp'd)
// grid: (B, 8); blockIdx.y = ni(2)*4 + ui(4); 64x64 tile, K=256
// ---------------------------------------------------------------------------
__global__ __launch_bounds__(256) void k_r2exp(const float* __restrict__ x,
                                               const float* __restrict__ Ue,
                                               float* __restrict__ Q){
  const int b  = blockIdx.x;
  const int n0 = (blockIdx.y >> 2) * 64;
  const int u0 = (blockIdx.y & 3) * 64;
  __shared__ float Al[16][68];
  __shared__ float Bl[16][68];
  const int tid  = threadIdx.x;
  const int lane = tid & 63;
  const int kq   = tid >> 6;
  const int ty   = tid >> 4;
  const int tx   = tid & 15;
  float acc[4][4] = {};
  const float* xb = x + (size_t)b * Tsz * Nsz;
  for (int k0 = 0; k0 < Tsz; k0 += 16){
    #pragma unroll
    for (int i = 0; i < 4; ++i){
      const int k = kq*4 + i;
      Al[k][lane] = xb[(size_t)(k0+k)*Nsz + n0 + lane];
      Bl[k][lane] = Ue[(size_t)(k0+k)*Tsz + u0 + lane];
    }
    __syncthreads();
    #pragma unroll
    for (int kk = 0; kk < 16; ++kk){
      const float4 a = *(const float4*)&Al[kk][ty*4];
      const float4 w = *(const float4*)&Bl[kk][tx*4];
      const float av[4] = {a.x,a.y,a.z,a.w};
      const float wv[4] = {w.x,w.y,w.z,w.w};
      #pragma unroll
      for (int i=0;i<4;++i)
        #pragma unroll
        for (int j=0;j<4;++j)
          acc[i][j] = fmaf(av[i], wv[j], acc[i][j]);
    }
    __syncthreads();
  }
  float* Qb = Q + (size_t)b * Nsz * Tsz;
  #pragma unroll
  for (int i=0;i<4;++i){
    float4 v;
    v.x = __expf(2.0f*acc[i][0]);
    v.y = __expf(2.0f*acc[i][1]);
    v.z = __expf(2.0f*acc[i][2]);
    v.w = __expf(2.0f*acc[i][3]);
    *(float4*)&Qb[(size_t)(n0 + ty*4 + i)*Tsz + u0 + tx*4] = v;
  }
}

// ---------------------------------------------------------------------------
// K2: one LSTM step. z = x_t@Wk + h_t@Wr + b; gates i,f,g,o (keras order).
// Reads fp32 h/s ping-pong, writes fp32 next + bf16 HS slab t+1.
// block tile: 64 b x (4 gates x 16 m) = 64x64, K = 128+256 = 384; grid (8,16)
// ---------------------------------------------------------------------------
__global__ __launch_bounds__(256) void k_step(const float* __restrict__ x,
                                              const float* __restrict__ Wk,
                                              const float* __restrict__ Wr,
                                              const float* __restrict__ bias,
                                              const float* __restrict__ h_cur,
                                              const float* __restrict__ s_cur,
                                              float* __restrict__ h_nxt,
                                              float* __restrict__ s_nxt,
                                              unsigned short* __restrict__ HS,
                                              const int t){
  const int b0 = blockIdx.x * 64;
  const int mi = blockIdx.y;            // m-tile: m0 = mi*16
  __shared__ float Al[16][68];          // [k][b]
  __shared__ float Wl[16][68];          // [k][col], col = g*16 + ml
  __shared__ float Zl[64][68];          // z tile [b][col]
  const int tid  = threadIdx.x;
  const int lane = tid & 63;
  const int kq   = tid >> 6;
  const int ty   = tid >> 4;
  const int tx   = tid & 15;
  const int g    = lane >> 4;
  const int ml   = lane & 15;
  const int jcol = g*Msz + mi*16 + ml;  // global z column for this lane's W load
  float acc[4][4] = {};
  for (int k0 = 0; k0 < Nsz + Msz; k0 += 16){
    const int kb = k0 + kq*4;
    float4 av;
    if (kb < Nsz){
      av = *(const float4*)(x + (size_t)(b0+lane)*Tsz*Nsz + (size_t)t*Nsz + kb);
    } else {
      av = *(const float4*)(h_cur + (size_t)(b0+lane)*Msz + (kb - Nsz));
    }
    Al[kq*4+0][lane] = av.x;
    Al[kq*4+1][lane] = av.y;
    Al[kq*4+2][lane] = av.z;
    Al[kq*4+3][lane] = av.w;
    #pragma unroll
    for (int i=0;i<4;++i){
      const int kk = k0 + kq*4 + i;
      Wl[kq*4+i][lane] = (kk < Nsz) ? Wk[(size_t)kk*(4*Msz) + jcol]
                                    : Wr[(size_t)(kk - Nsz)*(4*Msz) + jcol];
    }
    __syncthreads();
    #pragma unroll
    for (int kk=0; kk<16; ++kk){
      const float4 a = *(const float4*)&Al[kk][ty*4];
      const float4 w = *(const float4*)&Wl[kk][tx*4];
      const float av2[4] = {a.x,a.y,a.z,a.w};
      const float wv2[4] = {w.x,w.y,w.z,w.w};
      #pragma unroll
      for (int i=0;i<4;++i)
        #pragma unroll
        for (int j=0;j<4;++j)
          acc[i][j] = fmaf(av2[i], wv2[j], acc[i][j]);
    }
    __syncthreads();
  }
  // bias add + stage z tile to LDS
  #pragma unroll
  for (int j=0;j<4;++j){
    const int c  = tx*4 + j;
    const float bj = bias[(c>>4)*Msz + mi*16 + (c & 15)];
    #pragma unroll
    for (int i=0;i<4;++i)
      Zl[ty*4+i][c] = acc[i][j] + bj;
  }
  __syncthreads();
  // LSTM update: 64b x 16m, 4 consecutive m per thread
  {
    const int base = tid * 4;
    const int bl   = base >> 4;
    const int mlb  = base & 15;        // multiple of 4
    const int b    = b0 + bl;
    const int m    = mi*16 + mlb;
    const float4 so = *(const float4*)(s_cur + (size_t)b*Msz + m);
    const float sold[4] = {so.x, so.y, so.z, so.w};
    float hn[4], sn[4];
    #pragma unroll
    for (int q=0;q<4;++q){
      const int mm = mlb + q;
      const float zi = Zl[bl][ 0 + mm];
      const float zf = Zl[bl][16 + mm];
      const float zg = Zl[bl][32 + mm];
      const float zo = Zl[bl][48 + mm];
      const float ig = sigmoid_fast(zi);
      const float fg = sigmoid_fast(zf);
      const float gg = tanh_fast(zg);
      const float og = sigmoid_fast(zo);
      const float s1 = fmaf(fg, sold[q], ig * gg);
      sn[q] = s1;
      hn[q] = og * tanh_fast(s1);
    }
    *(float4*)(h_nxt + (size_t)b*Msz + m) = make_float4(hn[0],hn[1],hn[2],hn[3]);
    *(float4*)(s_nxt + (size_t)b*Msz + m) = make_float4(sn[0],sn[1],sn[2],sn[3]);
    unsigned short* row = HS + ((size_t)(t+1)*Bsz + b) * 512;
    ushort4 hb, sb;
    hb.x = bf16r(hn[0]); hb.y = bf16r(hn[1]); hb.z = bf16r(hn[2]); hb.w = bf16r(hn[3]);
    sb.x = bf16r(sn[0]); sb.y = bf16r(sn[1]); sb.z = bf16r(sn[2]); sb.w = bf16r(sn[3]);
    *(ushort4*)(row + m)       = hb;
    *(ushort4*)(row + 256 + m) = sb;
  }
}

// ---------------------------------------------------------------------------
// K3: attention. Per block (b, 16 t's):
//   (a) load HS rows (bf16 -> fp32 LDS)
//   (b) fused r1 GEMM + exp: Pl[r][u] = exp(2 * [h,s]@We)
//   (c) e[t,n] = -2 * sum_u ve[u] / (1 + Pl*Q)   (softmax-equivalent of ref)
//   (d) softmax over n, out = alpha * x
// ---------------------------------------------------------------------------
__global__ __launch_bounds__(256) void k_attn(const unsigned short* __restrict__ HS,
                                              const float* __restrict__ Q,
                                              const float* __restrict__ We,
                                              const float* __restrict__ ve,
                                              const float* __restrict__ x,
                                              float* __restrict__ out){
  const int b  = blockIdx.x;
  const int t0 = blockIdx.y * 16;
  __shared__ float HSl[16][512];   // 32 KB
  __shared__ float Pl[16][260];
  __shared__ float Ql[16][260];
  __shared__ float vel[256];
  __shared__ float El[16][128];
  __shared__ float red[16][16];
  __shared__ float rowm[16];
  __shared__ float rowsum[16];
  const int tid = threadIdx.x;
  vel[tid] = ve[tid];
  {
    const int row = tid >> 4;
    const int c0  = (tid & 15) * 32;
    const unsigned short* src = HS + ((size_t)(t0 + row) * Bsz + b) * 512 + c0;
    #pragma unroll
    for (int q = 0; q < 4; ++q){
      const uint4 v = *(const uint4*)(src + q * 8);
      const unsigned wv[4] = {v.x, v.y, v.z, v.w};
      #pragma unroll
      for (int e = 0; e < 4; ++e){
        HSl[row][c0 + q*8 + e*2 + 0] = __uint_as_float(wv[e] << 16);
        HSl[row][c0 + q*8 + e*2 + 1] = __uint_as_float(wv[e] & 0xFFFF0000u);
      }
    }
  }
  __syncthreads();
  // fused r1 GEMM + exp. wave w handles rows {w, w+4, w+8, w+12}; lane -> u = lane*4+j
  {
    const int lane = tid & 63;
    const int w    = tid >> 6;
    float acc[4][4] = {};
    for (int k = 0; k < 2*Msz; k += 4){
      float a[4][4];
      #pragma unroll
      for (int ri = 0; ri < 4; ++ri){
        const float4 t4 = *(const float4*)&HSl[w + 4*ri][k];
        a[ri][0]=t4.x; a[ri][1]=t4.y; a[ri][2]=t4.z; a[ri][3]=t4.w;
      }
      #pragma unroll
      for (int kk = 0; kk < 4; ++kk){
        const float4 wv = *(const float4*)(We + (size_t)(k+kk) * Tsz + lane*4);
        const float wa[4] = {wv.x, wv.y, wv.z, wv.w};
        #pragma unroll
        for (int ri=0; ri<4; ++ri)
          #pragma unroll
          for (int j=0;j<4;++j)
            acc[ri][j] = fmaf(a[ri][kk], wa[j], acc[ri][j]);
      }
    }
    #pragma unroll
    for (int ri = 0; ri < 4; ++ri)
      #pragma unroll
      for (int j = 0; j < 4; ++j)
        Pl[w + 4*ri][lane*4 + j] = __expf(2.0f * acc[ri][j]);
  }
  const int t  = tid >> 4;
  const int nl = tid & 15;
  for (int n0 = 0; n0 < Nsz; n0 += 16){
    __syncthreads();
    {
      const int row = tid >> 4;
      const int uc  = (tid & 15) * 16;
      const float* src = Q + ((size_t)b * Nsz + n0 + row) * Tsz + uc;
      #pragma unroll
      for (int i = 0; i < 4; ++i)
        *(float4*)&Ql[row][uc + i*4] = *(const float4*)&src[i*4];
    }
    __syncthreads();
    float acc = 0.0f;
    #pragma unroll 8
    for (int u = 0; u < Tsz; u += 4){
      const float4 p4 = *(const float4*)&Pl[t][u];
      const float4 q4 = *(const float4*)&Ql[nl][u];
      const float4 v4 = *(const float4*)&vel[u];
      acc = fmaf(v4.x, rcp_fast(fmaf(p4.x, q4.x, 1.0f)), acc);
      acc = fmaf(v4.y, rcp_fast(fmaf(p4.y, q4.y, 1.0f)), acc);
      acc = fmaf(v4.z, rcp_fast(fmaf(p4.z, q4.z, 1.0f)), acc);
      acc = fmaf(v4.w, rcp_fast(fmaf(p4.w, q4.w, 1.0f)), acc);
    }
    El[t][n0 + nl] = -2.0f * acc;
  }
  __syncthreads();
  // softmax over n (128) per t row; 16 threads per row, 8 n each
  const int j = nl;
  float mx = -3.0e38f;
  #pragma unroll
  for (int q=0;q<8;++q) mx = fmaxf(mx, El[t][j*8+q]);
  red[t][j] = mx;
  __syncthreads();
  if (j == 0){
    float m2 = red[t][0];
    #pragma unroll
    for (int q=1;q<16;++q) m2 = fmaxf(m2, red[t][q]);
    rowm[t] = m2;
  }
  __syncthreads();
  const float rm = rowm[t];
  float sm = 0.0f;
  #pragma unroll
  for (int q=0;q<8;++q){
    const float p = __expf(El[t][j*8+q] - rm);
    El[t][j*8+q] = p;
    sm += p;
  }
  red[t][j] = sm;
  __syncthreads();
  if (j == 0){
    float s2 = 0.0f;
    #pragma unroll
    for (int q=0;q<16;++q) s2 += red[t][q];
    rowsum[t] = s2;
  }
  __syncthreads();
  const float inv = rcp_fast(rowsum[t]);
  const float* xr   = x   + ((size_t)b*Tsz + t0 + t)*Nsz + j*8;
  float*       orow = out + ((size_t)b*Tsz + t0 + t)*Nsz + j*8;
  #pragma unroll
  for (int q=0;q<8;++q)
    orow[q] = El[t][j*8+q] * inv * xr[q];
}

// ---------------------------------------------------------------------------
extern "C" void kernel_launch(void* const* d_in, const int* in_sizes, int n_in,
                              void* d_out, int out_size, void* d_ws, size_t ws_size,
                              hipStream_t stream){
  const float* x    = (const float*)d_in[0];
  const float* s_in = (const float*)d_in[1];
  const float* h_in = (const float*)d_in[2];
  const float* We   = (const float*)d_in[3];
  const float* Ue   = (const float*)d_in[4];
  const float* ve   = (const float*)d_in[5];
  const float* Wk   = (const float*)d_in[6];
  const float* Wr   = (const float*)d_in[7];
  const float* bias = (const float*)d_in[8];
  float* out = (float*)d_out;

  // workspace layout (203 MB total):
  //   hp: 2 slots * B*M fp32   (1 MB * 2)
  //   sp: 2 slots * B*M fp32
  //   Q : B*N*T fp32           (67 MB)
  //   HS: T*B*512 bf16         (134 MB)
  const size_t BM = (size_t)Bsz * Msz;
  float* hp = (float*)d_ws;
  float* sp = hp + 2*BM;
  float* Q  = sp + 2*BM;
  unsigned short* HS = (unsigned short*)(Q + (size_t)Bsz*Nsz*Tsz);

  k_init<<<(int)(BM/256), 256, 0, stream>>>(h_in, s_in, hp, sp, HS);

  // Q = exp(2*r2)  (independent of the scan)
  k_r2exp<<<dim3(Bsz, 8), 256, 0, stream>>>(x, Ue, Q);

  // sequential LSTM recurrence: writes HS[1..255]
  for (int t = 0; t < Tsz - 1; ++t){
    const int cur = t & 1;
    k_step<<<dim3(Bsz/64, 16), 256, 0, stream>>>(x, Wk, Wr, bias,
                                                 hp + cur*BM, sp + cur*BM,
                                                 hp + (1-cur)*BM, sp + (1-cur)*BM,
                                                 HS, t);
  }

  // fused r1 + attention + softmax + out = alpha * x
  k_attn<<<dim3(Bsz, Tsz/16), 256, 0, stream>>>(HS, Q, We, ve, x, out);
}

// Round 3
// 3843.825 us; speedup vs baseline: 3.0779x; 3.0779x over previous
//
#include <hip/hip_runtime.h>

static constexpr int Bsz = 512;
static constexpr int Tsz = 256;
static constexpr int Nsz = 128;
static constexpr int Msz = 256;

using short8 = __attribute__((ext_vector_type(8))) short;
using f32x4  = __attribute__((ext_vector_type(4))) float;

__device__ __forceinline__ float rcp_fast(float v){ return __builtin_amdgcn_rcpf(v); }
__device__ __forceinline__ float sigmoid_fast(float v){ return rcp_fast(1.0f + __expf(-v)); }
__device__ __forceinline__ float tanh_fast(float v){ return 1.0f - 2.0f * rcp_fast(1.0f + __expf(2.0f * v)); }
__device__ __forceinline__ unsigned short bf16r(float f){
  unsigned u = __float_as_uint(f);
  u += 0x7FFFu + ((u >> 16) & 1u);
  return (unsigned short)(u >> 16);
}

// ---------------------------------------------------------------------------
// K0: HS slab t=0 (bf16 h,s) + zero the scan barrier counters.
// HS layout: [t][b][j], j<256 -> h, j>=256 -> s (bf16, row stride 512)
// ---------------------------------------------------------------------------
__global__ __launch_bounds__(256) void k_init(const float* __restrict__ h_in,
                                              const float* __restrict__ s_in,
                                              unsigned short* __restrict__ HS,
                                              int* __restrict__ ctr){
  const int i = blockIdx.x * 256 + threadIdx.x;   // 0 .. B*M-1 (131072)
  if (i < 2048) ctr[i] = 0;
  const float h = h_in[i];
  const float s = s_in[i];
  const int b = i >> 8;
  const int m = i & 255;
  unsigned short* row = HS + (size_t)b * 512;
  row[m]       = bf16r(h);
  row[256 + m] = bf16r(s);
}

// ---------------------------------------------------------------------------
// K1: Q[b][n][u] = exp( 2 * sum_t x[b][t][n] * Ue[t][u] )   (r2, pre-exp'd)
// ---------------------------------------------------------------------------
__global__ __launch_bounds__(256) void k_r2exp(const float* __restrict__ x,
                                               const float* __restrict__ Ue,
                                               float* __restrict__ Q){
  const int b  = blockIdx.x;
  const int n0 = (blockIdx.y >> 2) * 64;
  const int u0 = (blockIdx.y & 3) * 64;
  __shared__ float Al[16][68];
  __shared__ float Bl[16][68];
  const int tid  = threadIdx.x;
  const int lane = tid & 63;
  const int kq   = tid >> 6;
  const int ty   = tid >> 4;
  const int tx   = tid & 15;
  float acc[4][4] = {};
  const float* xb = x + (size_t)b * Tsz * Nsz;
  for (int k0 = 0; k0 < Tsz; k0 += 16){
    #pragma unroll
    for (int i = 0; i < 4; ++i){
      const int k = kq*4 + i;
      Al[k][lane] = xb[(size_t)(k0+k)*Nsz + n0 + lane];
      Bl[k][lane] = Ue[(size_t)(k0+k)*Tsz + u0 + lane];
    }
    __syncthreads();
    #pragma unroll
    for (int kk = 0; kk < 16; ++kk){
      const float4 a = *(const float4*)&Al[kk][ty*4];
      const float4 w = *(const float4*)&Bl[kk][tx*4];
      const float av[4] = {a.x,a.y,a.z,a.w};
      const float wv[4] = {w.x,w.y,w.z,w.w};
      #pragma unroll
      for (int i=0;i<4;++i)
        #pragma unroll
        for (int j=0;j<4;++j)
          acc[i][j] = fmaf(av[i], wv[j], acc[i][j]);
    }
    __syncthreads();
  }
  float* Qb = Q + (size_t)b * Nsz * Tsz;
  #pragma unroll
  for (int i=0;i<4;++i){
    float4 v;
    v.x = __expf(2.0f*acc[i][0]);
    v.y = __expf(2.0f*acc[i][1]);
    v.z = __expf(2.0f*acc[i][2]);
    v.w = __expf(2.0f*acc[i][3]);
    *(float4*)&Qb[(size_t)(n0 + ty*4 + i)*Tsz + u0 + tx*4] = v;
  }
}

// ---------------------------------------------------------------------------
// K2: persistent LSTM scan. 128 blocks = 8 batch-groups(64 b) x 16 unit-groups
// (16 units -> 64 z-cols: 4 gates x 16). W fragments preloaded to registers
// (time-invariant). Per step: stage A=[x_t | h_t] bf16 to LDS (chunk-major),
// 12x4 MFMA 16x16x32, in-register gate update (s fp32 in regs), write h,s
// bf16 to HS[t+1], 16-block group barrier (release add / acquire spin).
// ---------------------------------------------------------------------------
__global__ __launch_bounds__(256, 1) void k_scan(const float* __restrict__ x,
                                                 const float* __restrict__ Wk,
                                                 const float* __restrict__ Wr,
                                                 const float* __restrict__ bias,
                                                 const float* __restrict__ s_in,
                                                 unsigned short* __restrict__ HS,
                                                 int* __restrict__ ctr){
  const int bg = blockIdx.x >> 4;     // batch group 0..7
  const int ug = blockIdx.x & 15;     // unit group 0..15
  const int b0 = bg * 64;
  const int u0 = ug * 16;
  const int tid  = threadIdx.x;
  const int w    = tid >> 6;          // wave 0..3 -> rows w*16..w*16+15
  const int lane = tid & 63;
  const int nl   = lane & 15;         // tile col / A row-within-tile
  const int kq   = lane >> 4;         // k quad

  __shared__ unsigned short Al[12*64*32];   // [chunk][row][32k] bf16, 48 KB

  // ---- preload W fragments (bf16) into registers: 12 chunks x 4 gates ----
  short8 wf[12][4];
  #pragma unroll
  for (int c = 0; c < 12; ++c){
    #pragma unroll
    for (int g = 0; g < 4; ++g){
      const int jcol = g*Msz + u0 + nl;
      short8 f;
      #pragma unroll
      for (int j = 0; j < 8; ++j){
        const int k = c*32 + kq*8 + j;
        const float wv = (k < Nsz) ? Wk[(size_t)k*(4*Msz) + jcol]
                                   : Wr[(size_t)(k - Nsz)*(4*Msz) + jcol];
        f[j] = (short)bf16r(wv);
      }
      wf[c][g] = f;
    }
  }

  // ---- per-lane state: 4 batch rows x 1 unit ----
  const int r0 = w*16 + kq*4;                 // first of 4 rows (C-layout)
  float bi[4];
  #pragma unroll
  for (int g = 0; g < 4; ++g) bi[g] = bias[g*Msz + u0 + nl];
  float s_reg[4];
  #pragma unroll
  for (int r = 0; r < 4; ++r)
    s_reg[r] = s_in[(size_t)(b0 + r0 + r)*Msz + u0 + nl];

  #pragma unroll 1
  for (int t = 0; t < Tsz - 1; ++t){
    __syncthreads();   // LDS WAR vs previous step's frag reads
    // ---- stage x_t (fp32 -> bf16): 64 rows x 128 n ----
    #pragma unroll
    for (int q = 0; q < 8; ++q){
      const int seg = tid*8 + q;              // 0..2047
      const int row = seg >> 5;
      const int n   = (seg & 31) * 4;
      const float4 v = *(const float4*)(x + ((size_t)(b0+row)*Tsz + t)*Nsz + n);
      ushort4 o;
      o.x = bf16r(v.x); o.y = bf16r(v.y); o.z = bf16r(v.z); o.w = bf16r(v.w);
      *(ushort4*)&Al[(n >> 5)*2048 + row*32 + (n & 31)] = o;
    }
    // ---- stage h_t (bf16 copy): 64 rows x 256 m ----
    #pragma unroll
    for (int q = 0; q < 8; ++q){
      const int seg = tid*8 + q;              // 0..2047
      const int row = seg >> 5;
      const int m   = (seg & 31) * 8;
      const uint4 v = *(const uint4*)(HS + ((size_t)t*Bsz + b0 + row)*512 + m);
      const int k = 128 + m;
      *(uint4*)&Al[(k >> 5)*2048 + row*32 + (k & 31)] = v;
    }
    __syncthreads();

    // ---- z GEMM: 12 chunks x 4 gate-tiles of mfma 16x16x32 bf16 ----
    f32x4 acc0 = {0.f,0.f,0.f,0.f}, acc1 = {0.f,0.f,0.f,0.f};
    f32x4 acc2 = {0.f,0.f,0.f,0.f}, acc3 = {0.f,0.f,0.f,0.f};
    #pragma unroll
    for (int c = 0; c < 12; ++c){
      const short8 af = *(const short8*)&Al[c*2048 + (w*16 + nl)*32 + kq*8];
      acc0 = __builtin_amdgcn_mfma_f32_16x16x32_bf16(af, wf[c][0], acc0, 0, 0, 0);
      acc1 = __builtin_amdgcn_mfma_f32_16x16x32_bf16(af, wf[c][1], acc1, 0, 0, 0);
      acc2 = __builtin_amdgcn_mfma_f32_16x16x32_bf16(af, wf[c][2], acc2, 0, 0, 0);
      acc3 = __builtin_amdgcn_mfma_f32_16x16x32_bf16(af, wf[c][3], acc3, 0, 0, 0);
    }

    // ---- gate update (in-register; C layout: col=nl, row=r0+r) ----
    #pragma unroll
    for (int r = 0; r < 4; ++r){
      const float ig = sigmoid_fast(acc0[r] + bi[0]);
      const float fg = sigmoid_fast(acc1[r] + bi[1]);
      const float gg = tanh_fast  (acc2[r] + bi[2]);
      const float og = sigmoid_fast(acc3[r] + bi[3]);
      const float s1 = fmaf(fg, s_reg[r], ig * gg);
      s_reg[r] = s1;
      const float hn = og * tanh_fast(s1);
      unsigned short* rp = HS + ((size_t)(t+1)*Bsz + b0 + r0 + r)*512;
      rp[u0 + nl]        = bf16r(hn);
      rp[256 + u0 + nl]  = bf16r(s1);
    }

    // ---- group barrier: 16 unit-blocks of this batch group ----
    __syncthreads();
    if (tid == 0){
      int* c = &ctr[t*8 + bg];
      __hip_atomic_fetch_add(c, 1, __ATOMIC_RELEASE, __HIP_MEMORY_SCOPE_AGENT);
      while (__hip_atomic_load(c, __ATOMIC_ACQUIRE, __HIP_MEMORY_SCOPE_AGENT) < 16){
        __builtin_amdgcn_s_sleep(2);
      }
    }
    __syncthreads();
  }
}

// ---------------------------------------------------------------------------
// K3: attention. Per block (b, 16 t's): HS bf16 -> fp32 LDS; fused r1 GEMM +
// exp; e = -2*sum_u ve_u/(1+P*Q) (softmax-equivalent); softmax; out=alpha*x.
// ---------------------------------------------------------------------------
__global__ __launch_bounds__(256) void k_attn(const unsigned short* __restrict__ HS,
                                              const float* __restrict__ Q,
                                              const float* __restrict__ We,
                                              const float* __restrict__ ve,
                                              const float* __restrict__ x,
                                              float* __restrict__ out){
  const int b  = blockIdx.x;
  const int t0 = blockIdx.y * 16;
  __shared__ float HSl[16][512];
  __shared__ float Pl[16][260];
  __shared__ float Ql[16][260];
  __shared__ float vel[256];
  __shared__ float El[16][128];
  __shared__ float red[16][16];
  __shared__ float rowm[16];
  __shared__ float rowsum[16];
  const int tid = threadIdx.x;
  vel[tid] = ve[tid];
  {
    const int row = tid >> 4;
    const int c0  = (tid & 15) * 32;
    const unsigned short* src = HS + ((size_t)(t0 + row) * Bsz + b) * 512 + c0;
    #pragma unroll
    for (int q = 0; q < 4; ++q){
      const uint4 v = *(const uint4*)(src + q * 8);
      const unsigned wv[4] = {v.x, v.y, v.z, v.w};
      #pragma unroll
      for (int e = 0; e < 4; ++e){
        HSl[row][c0 + q*8 + e*2 + 0] = __uint_as_float(wv[e] << 16);
        HSl[row][c0 + q*8 + e*2 + 1] = __uint_as_float(wv[e] & 0xFFFF0000u);
      }
    }
  }
  __syncthreads();
  {
    const int lane = tid & 63;
    const int w    = tid >> 6;
    float acc[4][4] = {};
    for (int k = 0; k < 2*Msz; k += 4){
      float a[4][4];
      #pragma unroll
      for (int ri = 0; ri < 4; ++ri){
        const float4 t4 = *(const float4*)&HSl[w + 4*ri][k];
        a[ri][0]=t4.x; a[ri][1]=t4.y; a[ri][2]=t4.z; a[ri][3]=t4.w;
      }
      #pragma unroll
      for (int kk = 0; kk < 4; ++kk){
        const float4 wv = *(const float4*)(We + (size_t)(k+kk) * Tsz + lane*4);
        const float wa[4] = {wv.x, wv.y, wv.z, wv.w};
        #pragma unroll
        for (int ri=0; ri<4; ++ri)
          #pragma unroll
          for (int j=0;j<4;++j)
            acc[ri][j] = fmaf(a[ri][kk], wa[j], acc[ri][j]);
      }
    }
    #pragma unroll
    for (int ri = 0; ri < 4; ++ri)
      #pragma unroll
      for (int j = 0; j < 4; ++j)
        Pl[w + 4*ri][lane*4 + j] = __expf(2.0f * acc[ri][j]);
  }
  const int t  = tid >> 4;
  const int nl = tid & 15;
  for (int n0 = 0; n0 < Nsz; n0 += 16){
    __syncthreads();
    {
      const int row = tid >> 4;
      const int uc  = (tid & 15) * 16;
      const float* src = Q + ((size_t)b * Nsz + n0 + row) * Tsz + uc;
      #pragma unroll
      for (int i = 0; i < 4; ++i)
        *(float4*)&Ql[row][uc + i*4] = *(const float4*)&src[i*4];
    }
    __syncthreads();
    float acc = 0.0f;
    #pragma unroll 8
    for (int u = 0; u < Tsz; u += 4){
      const float4 p4 = *(const float4*)&Pl[t][u];
      const float4 q4 = *(const float4*)&Ql[nl][u];
      const float4 v4 = *(const float4*)&vel[u];
      acc = fmaf(v4.x, rcp_fast(fmaf(p4.x, q4.x, 1.0f)), acc);
      acc = fmaf(v4.y, rcp_fast(fmaf(p4.y, q4.y, 1.0f)), acc);
      acc = fmaf(v4.z, rcp_fast(fmaf(p4.z, q4.z, 1.0f)), acc);
      acc = fmaf(v4.w, rcp_fast(fmaf(p4.w, q4.w, 1.0f)), acc);
    }
    El[t][n0 + nl] = -2.0f * acc;
  }
  __syncthreads();
  const int j = nl;
  float mx = -3.0e38f;
  #pragma unroll
  for (int q=0;q<8;++q) mx = fmaxf(mx, El[t][j*8+q]);
  red[t][j] = mx;
  __syncthreads();
  if (j == 0){
    float m2 = red[t][0];
    #pragma unroll
    for (int q=1;q<16;++q) m2 = fmaxf(m2, red[t][q]);
    rowm[t] = m2;
  }
  __syncthreads();
  const float rm = rowm[t];
  float sm = 0.0f;
  #pragma unroll
  for (int q=0;q<8;++q){
    const float p = __expf(El[t][j*8+q] - rm);
    El[t][j*8+q] = p;
    sm += p;
  }
  red[t][j] = sm;
  __syncthreads();
  if (j == 0){
    float s2 = 0.0f;
    #pragma unroll
    for (int q=0;q<16;++q) s2 += red[t][q];
    rowsum[t] = s2;
  }
  __syncthreads();
  const float inv = rcp_fast(rowsum[t]);
  const float* xr   = x   + ((size_t)b*Tsz + t0 + t)*Nsz + j*8;
  float*       orow = out + ((size_t)b*Tsz + t0 + t)*Nsz + j*8;
  #pragma unroll
  for (int q=0;q<8;++q)
    orow[q] = El[t][j*8+q] * inv * xr[q];
}

// ---------------------------------------------------------------------------
extern "C" void kernel_launch(void* const* d_in, const int* in_sizes, int n_in,
                              void* d_out, int out_size, void* d_ws, size_t ws_size,
                              hipStream_t stream){
  const float* x    = (const float*)d_in[0];
  const float* s_in = (const float*)d_in[1];
  const float* h_in = (const float*)d_in[2];
  const float* We   = (const float*)d_in[3];
  const float* Ue   = (const float*)d_in[4];
  const float* ve   = (const float*)d_in[5];
  const float* Wk   = (const float*)d_in[6];
  const float* Wr   = (const float*)d_in[7];
  const float* bias = (const float*)d_in[8];
  float* out = (float*)d_out;

  // ws layout (~201.3 MB): Q fp32 67MB | HS bf16 134MB | ctr 8KB
  float* Q = (float*)d_ws;
  unsigned short* HS = (unsigned short*)(Q + (size_t)Bsz*Nsz*Tsz);
  int* ctr = (int*)(HS + (size_t)Tsz*Bsz*512);

  k_init<<<(Bsz*Msz)/256, 256, 0, stream>>>(h_in, s_in, HS, ctr);
  k_r2exp<<<dim3(Bsz, 8), 256, 0, stream>>>(x, Ue, Q);
  k_scan<<<128, 256, 0, stream>>>(x, Wk, Wr, bias, s_in, HS, ctr);
  k_attn<<<dim3(Bsz, Tsz/16), 256, 0, stream>>>(HS, Q, We, ve, x, out);
}